// Round 1
// baseline (131.513 us; speedup 1.0000x reference)
//
#include <hip/hip_runtime.h>

// AdaptiveFourierPositionEncoding
// B=8, S=32768, DIM=128, NUM_BANDS=64. Tokens = B*S = 262144.
// One wave (64 lanes) per token; lane n owns band n.
// W row (128 f32) lives in VGPRs per lane; x row staged in LDS, read via
// same-address broadcast (free); softmax via shfl_xor; sin/cos via f64
// range-reduction to revolutions + raw v_sin_f32/v_cos_f32.

#define NTOK (8 * 32768)
#define DIM 128
#define NB 64

__global__ __launch_bounds__(256, 2) void afpe_kernel(
    const float* __restrict__ x,
    const int*   __restrict__ positions,
    const float* __restrict__ fb,
    const float* __restrict__ ph,
    const float* __restrict__ aw,
    const float* __restrict__ ab,
    float* __restrict__ out)
{
    __shared__ float4 xs4[4][32];   // per-wave staging row (128 f32, 16B aligned)
    const int lane = threadIdx.x & 63;
    const int wv   = threadIdx.x >> 6;
    const int gw   = blockIdx.x * 4 + wv;     // global wave id
    const int nw   = gridDim.x * 4;           // total waves

    // per-lane band parameters
    const float freq = fb[lane];
    const float phs  = ph[lane];
    const float bias = ab[lane];

    // band weight row -> 128 VGPRs
    float w[DIM];
    {
        const float4* wrow = (const float4*)(aw + lane * DIM);
        #pragma unroll
        for (int i = 0; i < 32; ++i) {
            float4 t = wrow[i];
            w[4*i+0] = t.x; w[4*i+1] = t.y; w[4*i+2] = t.z; w[4*i+3] = t.w;
        }
    }

    const float2* x2 = (const float2*)x;
    float2*       o2 = (float2*)out;

    int tok = gw;
    if (tok >= NTOK) return;

    // prologue load (prefetch pipeline)
    float2 xv = x2[(size_t)tok * 64 + lane];
    int    p  = positions[tok];

    for (; tok < NTOK; tok += nw) {
        // stage current x row to this wave's LDS row
        ((float2*)&xs4[wv][0])[lane] = xv;

        // prefetch next token (hide HBM latency under the dot product)
        const int ntok = tok + nw;
        float2 xv_n = make_float2(0.f, 0.f);
        int    p_n  = 0;
        if (ntok < NTOK) {
            xv_n = x2[(size_t)ntok * 64 + lane];
            p_n  = positions[ntok];
        }

        // logit for band `lane`: dot(x_row, w_row) + bias
        float acc = bias;
        #pragma unroll
        for (int k4 = 0; k4 < 32; ++k4) {
            const float4 xq = xs4[wv][k4];     // broadcast: all lanes same addr
            acc = fmaf(xq.x, w[4*k4+0], acc);
            acc = fmaf(xq.y, w[4*k4+1], acc);
            acc = fmaf(xq.z, w[4*k4+2], acc);
            acc = fmaf(xq.w, w[4*k4+3], acc);
        }

        // softmax over the 64 bands (one per lane); logits are O(+-6) so no
        // max-subtraction needed for f32 exp
        const float e = __expf(acc);
        float s = e;
        #pragma unroll
        for (int m = 32; m >= 1; m >>= 1) s += __shfl_xor(s, m, 64);
        const float attn = e / s;

        // encoding: angle computed exactly as reference (f32 mul + f32 add),
        // then range-reduce in f64 to revolutions for the HW sin/cos
        float ang = (float)p * freq;
        ang = ang + phs;
        double t = (double)ang * 0.15915494309189535; // 1/(2*pi)
        t -= floor(t);
        const float rev = (float)t;
        const float sn = __builtin_amdgcn_sinf(rev);  // sin(2*pi*rev)
        const float cn = __builtin_amdgcn_cosf(rev);  // cos(2*pi*rev)

        // out[2n] = x[2n] + sin*attn ; out[2n+1] = x[2n+1] + cos*attn
        float2 ov;
        ov.x = xv.x + sn * attn;
        ov.y = xv.y + cn * attn;
        o2[(size_t)tok * 64 + lane] = ov;

        xv = xv_n;
        p  = p_n;
    }
}

extern "C" void kernel_launch(void* const* d_in, const int* in_sizes, int n_in,
                              void* d_out, int out_size, void* d_ws, size_t ws_size,
                              hipStream_t stream) {
    const float* x   = (const float*)d_in[0];
    const int*   pos = (const int*)d_in[1];
    const float* fb  = (const float*)d_in[2];
    const float* ph  = (const float*)d_in[3];
    const float* aw  = (const float*)d_in[4];
    const float* ab  = (const float*)d_in[5];
    float* out = (float*)d_out;

    // 512 blocks * 4 waves = 2048 waves (exactly resident at 2 waves/SIMD);
    // 128 tokens per wave, no divergent tail.
    afpe_kernel<<<512, 256, 0, stream>>>(x, pos, fb, ph, aw, ab, out);
}

// Round 2
// 58.465 us; speedup vs baseline: 2.2494x; 2.2494x over previous
//
#include <hip/hip_runtime.h>
#include <hip/hip_bf16.h>

// AdaptiveFourierPositionEncoding — MFMA restructure.
// B=8, S=32768, DIM=128, NB=64. Tokens=262144, processed as 16384 tiles of
// 16 tokens. One wave per tile-stream (8 tiles/wave, 2048 waves).
// Per tile: logits[64 bands][16 tokens] = W(bf16) x X^T(bf16) via 16x
// mfma_f32_16x16x32_bf16; softmax/trig/output all lane-local because the
// D-fragment band mapping (16m + (l>>4)*4 + r) == k-chunk band mapping
// ((k=(l>>4)*8+32c+i)/2) with m==c, r==i/2.

#define NTOK   (8 * 32768)
#define NTILE  (NTOK / 16)        // 16384
#define NWAVES 2048
#define TPW    (NTILE / NWAVES)   // 8 tiles per wave

typedef short  bf16x8 __attribute__((ext_vector_type(8)));
typedef float  f32x4  __attribute__((ext_vector_type(4)));

static __device__ __forceinline__ short f2bf(float f) {
    __hip_bfloat16 h = __float2bfloat16(f);   // RNE
    return __builtin_bit_cast(short, h);
}

// Stage one 16x128 f32 tile (8 KB) into LDS, 16B-granule XOR-swizzled:
// logical granule (t,u) is stored at t*32 + (u ^ (t&7)). Swizzle is applied
// by permuting the per-lane GLOBAL source address; LDS dest stays linear
// (global_load_lds requirement). Each instr moves 1 KB, fully coalesced
// (permutation stays within two contiguous 512B rows).
static __device__ __forceinline__ void stage_tile(const float* __restrict__ xtile,
                                                  char* ldsbuf, int lane) {
    #pragma unroll
    for (int j = 0; j < 8; ++j) {
        const int gp = 64 * j + lane;          // stored granule index
        const int t  = gp >> 5;                // token row 0..15
        const int u  = (gp & 31) ^ (t & 7);    // logical granule within row
        __builtin_amdgcn_global_load_lds(
            (const __attribute__((address_space(1))) void*)((const char*)xtile + t * 512 + u * 16),
            (__attribute__((address_space(3))) void*)(ldsbuf + j * 1024),
            16, 0, 0);
    }
}

__global__ __launch_bounds__(256, 2) void afpe_mfma(
    const float* __restrict__ x, const int* __restrict__ pos,
    const float* __restrict__ fb, const float* __restrict__ ph,
    const float* __restrict__ aw, const float* __restrict__ ab,
    float* __restrict__ out)
{
    __shared__ __align__(16) char lds[4][2][8192];   // per-wave double buffer
    const int lane = threadIdx.x & 63;
    const int wv   = threadIdx.x >> 6;
    const int gw   = blockIdx.x * 4 + wv;     // global wave id, 0..2047
    const int q    = lane >> 4;               // k-group / D-row group
    const int tt   = lane & 15;               // token-in-tile / A-row

    // A fragments: W[64][128] -> bf16, held in VGPRs for the whole kernel.
    // A[m][c] element i = W[16m + tt][q*8 + 32c + i]
    bf16x8 A[4][4];
    #pragma unroll
    for (int m = 0; m < 4; ++m) {
        #pragma unroll
        for (int c = 0; c < 4; ++c) {
            const float* wp = aw + (size_t)(16 * m + tt) * 128 + q * 8 + 32 * c;
            const float4 w0 = *(const float4*)wp;
            const float4 w1 = *(const float4*)(wp + 4);
            bf16x8 a;
            a[0] = f2bf(w0.x); a[1] = f2bf(w0.y); a[2] = f2bf(w0.z); a[3] = f2bf(w0.w);
            a[4] = f2bf(w1.x); a[5] = f2bf(w1.y); a[6] = f2bf(w1.z); a[7] = f2bf(w1.w);
            A[m][c] = a;
        }
    }
    // per-lane band params for bands q*4 + 16m + r  (r=0..3)
    float4 fbv[4], phv[4], abv[4];
    #pragma unroll
    for (int m = 0; m < 4; ++m) {
        fbv[m] = *(const float4*)(fb + q * 4 + 16 * m);
        phv[m] = *(const float4*)(ph + q * 4 + 16 * m);
        abv[m] = *(const float4*)(ab + q * 4 + 16 * m);
    }

    char* buf0 = lds[wv][0];
    char* buf1 = lds[wv][1];

    int tile = gw;
    stage_tile(x + (size_t)tile * 2048, buf0, lane);

    #pragma unroll
    for (int it = 0; it < TPW; ++it) {
        char* cur = (it & 1) ? buf1 : buf0;
        char* nxt = (it & 1) ? buf0 : buf1;
        const int ntile = tile + NWAVES;
        if (it < TPW - 1)
            stage_tile(x + (size_t)ntile * 2048, nxt, lane);
        const int p = pos[tile * 16 + tt];

        // Drain current tile's 8 staging loads; keep next tile's 8 + pos load
        // in flight (vmcnt counts retire in issue order).
        if (it < TPW - 1) asm volatile("s_waitcnt vmcnt(9)" ::: "memory");
        else              asm volatile("s_waitcnt vmcnt(1)" ::: "memory");

        // x fragments: lane reads its token row tt, k = q*8 + 32c + 4h .. +3
        float4 xf[8];
        #pragma unroll
        for (int c = 0; c < 4; ++c) {
            #pragma unroll
            for (int h = 0; h < 2; ++h) {
                const int u = 2 * q + 8 * c + h;               // logical granule
                const int g = tt * 32 + (u ^ (tt & 7));        // swizzled store
                xf[c * 2 + h] = *(const float4*)(cur + g * 16);
            }
        }

        // bf16 B fragments
        bf16x8 B[4];
        #pragma unroll
        for (int c = 0; c < 4; ++c) {
            const float4 b0 = xf[2 * c], b1 = xf[2 * c + 1];
            bf16x8 bv;
            bv[0] = f2bf(b0.x); bv[1] = f2bf(b0.y); bv[2] = f2bf(b0.z); bv[3] = f2bf(b0.w);
            bv[4] = f2bf(b1.x); bv[5] = f2bf(b1.y); bv[6] = f2bf(b1.z); bv[7] = f2bf(b1.w);
            B[c] = bv;
        }

        // logits: acc[m] reg r = logit[band 16m + q*4 + r][token tt], bias-seeded
        f32x4 acc[4];
        #pragma unroll
        for (int m = 0; m < 4; ++m) {
            acc[m][0] = abv[m].x; acc[m][1] = abv[m].y;
            acc[m][2] = abv[m].z; acc[m][3] = abv[m].w;
        }
        #pragma unroll
        for (int c = 0; c < 4; ++c) {
            #pragma unroll
            for (int m = 0; m < 4; ++m)
                acc[m] = __builtin_amdgcn_mfma_f32_16x16x32_bf16(A[m][c], B[c], acc[m], 0, 0, 0);
        }

        // softmax over 64 bands of token tt: local 16 + lanes tt+16/32/48
        float e[4][4];
        float s = 0.f;
        #pragma unroll
        for (int m = 0; m < 4; ++m) {
            #pragma unroll
            for (int r = 0; r < 4; ++r) { e[m][r] = __expf(acc[m][r]); s += e[m][r]; }
        }
        s += __shfl_xor(s, 16, 64);
        s += __shfl_xor(s, 32, 64);
        const float rinv = 1.0f / s;

        // trig (f64 range reduction to revolutions, matches f32 reference angle)
        const float pf = (float)p;
        float sa[4][4], ca[4][4];
        #pragma unroll
        for (int m = 0; m < 4; ++m) {
            const float fq[4] = {fbv[m].x, fbv[m].y, fbv[m].z, fbv[m].w};
            const float pp[4] = {phv[m].x, phv[m].y, phv[m].z, phv[m].w};
            #pragma unroll
            for (int r = 0; r < 4; ++r) {
                float ang = pf * fq[r];
                ang = ang + pp[r];
                double td = (double)ang * 0.15915494309189535;  // 1/(2*pi)
                td -= floor(td);
                const float rev = (float)td;
                const float at  = e[m][r] * rinv;
                sa[m][r] = __builtin_amdgcn_sinf(rev) * at;
                ca[m][r] = __builtin_amdgcn_cosf(rev) * at;
            }
        }

        // out[tt][k] = x + {sin,cos}*attn ; bands of chunk c == acc[c]
        float* ob = out + (size_t)(tile * 16 + tt) * 128 + q * 8;
        #pragma unroll
        for (int c = 0; c < 4; ++c) {
            #pragma unroll
            for (int h = 0; h < 2; ++h) {
                const float4 xv = xf[2 * c + h];
                float4 o;
                o.x = xv.x + sa[c][2 * h];
                o.y = xv.y + ca[c][2 * h];
                o.z = xv.z + sa[c][2 * h + 1];
                o.w = xv.w + ca[c][2 * h + 1];
                *(float4*)(ob + 32 * c + 4 * h) = o;
            }
        }
        tile = ntile;
    }
}

extern "C" void kernel_launch(void* const* d_in, const int* in_sizes, int n_in,
                              void* d_out, int out_size, void* d_ws, size_t ws_size,
                              hipStream_t stream) {
    const float* x   = (const float*)d_in[0];
    const int*   pos = (const int*)d_in[1];
    const float* fb  = (const float*)d_in[2];
    const float* ph  = (const float*)d_in[3];
    const float* aw  = (const float*)d_in[4];
    const float* ab  = (const float*)d_in[5];
    float* out = (float*)d_out;

    // 512 blocks x 4 waves = 2048 waves; 8 tiles (128 tokens) each, no tail.
    afpe_mfma<<<512, 256, 0, stream>>>(x, pos, fb, ph, aw, ab, out);
}